// Round 5
// baseline (232.923 us; speedup 1.0000x reference)
//
#include <hip/hip_runtime.h>

#define D 128
#define NB_MAX 1024   // max final buckets (128 rows each; n_nodes/128 = 782)
#define NSB_MAX 64    // max super-buckets (2048 rows = 16 buckets each)
#define CH1 4096      // edges per P1 block
#define CAP 2560      // LDS edge capacity per bucket (mean 2046, +11 sigma)
#define SP 136        // padded LDS row stride (bf16 elems) for y tile

typedef short short8 __attribute__((ext_vector_type(8)));
typedef float floatx4 __attribute__((ext_vector_type(4)));

__device__ inline unsigned short f2bf(float f) {
  unsigned u = __float_as_uint(f);
  u += 0x7fffu + ((u >> 16) & 1u);   // round-to-nearest-even
  return (unsigned short)(u >> 16);
}

// ---------------------------------------------------------------------------
// K1: fused wf_pack (blocks 0..7) + final-bucket histogram (bucket = row>>7).
// wf[ks][nt][lane][j] = W[ks*32 + (lane>>4)*8 + j][nt*16 + (lane&15)]  (bf16)
// ---------------------------------------------------------------------------
__global__ __launch_bounds__(256) void prep_kernel(
    const float* __restrict__ W, unsigned short* __restrict__ wf,
    const int* __restrict__ rows, int* __restrict__ bucket_cnt, int n_edges) {
  __shared__ int h[NB_MAX];
  const int bid = blockIdx.x;
  const int t = threadIdx.x;

  if (bid < 8) {           // ---- wf_pack role ----
    int tid = bid * 256 + t;            // 0..2047
    int ks = tid >> 9;
    int rem = tid & 511;
    int nt = rem >> 6;
    int lane = rem & 63;
    int n = nt * 16 + (lane & 15);
    int k0 = ks * 32 + (lane >> 4) * 8;
    unsigned short v[8];
#pragma unroll
    for (int j = 0; j < 8; ++j) v[j] = f2bf(W[(k0 + j) * D + n]);
    uint4 o;
    o.x = (unsigned)v[0] | ((unsigned)v[1] << 16);
    o.y = (unsigned)v[2] | ((unsigned)v[3] << 16);
    o.z = (unsigned)v[4] | ((unsigned)v[5] << 16);
    o.w = (unsigned)v[6] | ((unsigned)v[7] << 16);
    ((uint4*)wf)[tid] = o;
    return;
  }

  // ---- histogram role ----
  for (int i = t; i < NB_MAX; i += 256) h[i] = 0;
  __syncthreads();
  int blk = bid - 8;
  int lo = blk * 4096;
  int hi = min(lo + 4096, n_edges);
  for (int i = lo + t; i < hi; i += 256) atomicAdd(&h[rows[i] >> 7], 1);
  __syncthreads();
  for (int i = t; i < NB_MAX; i += 256)
    if (h[i]) atomicAdd(&bucket_cnt[i], h[i]);
}

// ---------------------------------------------------------------------------
// K2: scan bucket counts -> bucket_off + bucket_cursor (=off), and derive
// super-bucket offsets/cursors (sb = bucket>>4). One 1024-thread block.
// ---------------------------------------------------------------------------
__global__ __launch_bounds__(1024) void bucket_scan_kernel(
    const int* __restrict__ bucket_cnt, int* __restrict__ bucket_off,
    int* __restrict__ bucket_cursor, int* __restrict__ sb_off,
    int* __restrict__ sb_cursor, int nb) {
  __shared__ int s[1024];
  int t = threadIdx.x;
  s[t] = (t < nb) ? bucket_cnt[t] : 0;
  __syncthreads();
  for (int d = 1; d < 1024; d <<= 1) {
    int v = (t >= d) ? s[t - d] : 0;
    __syncthreads();
    s[t] += v;
    __syncthreads();
  }
  int excl = (t == 0) ? 0 : s[t - 1];
  if (t < nb) {
    bucket_off[t] = excl;
    bucket_cursor[t] = excl;
    if ((t & 15) == 0) { sb_off[t >> 4] = excl; sb_cursor[t >> 4] = excl; }
  }
  if (t == nb) {
    int total = s[nb - 1];
    bucket_off[nb] = total;
    sb_off[(nb + 15) >> 4] = total;
  }
}

// ---------------------------------------------------------------------------
// K3 (P1): partition edges into 49 super-bucket regions (sb = row>>11).
// Payload keeps 11 local-row bits: ((row&2047)<<17)|col , val.
// Runs per (block,sb) ~ 84 edges = 10.5 lines -> single-owner cache lines.
// ---------------------------------------------------------------------------
__global__ __launch_bounds__(256) void sb_partition_kernel(
    const int* __restrict__ rows, const int* __restrict__ cols,
    const float* __restrict__ vals, int* __restrict__ sb_cursor,
    int2* __restrict__ tmp1, int n_edges) {
  __shared__ int h[NSB_MAX];
  __shared__ int base_s[NSB_MAX];
  int t = threadIdx.x;
  if (t < NSB_MAX) h[t] = 0;
  __syncthreads();
  int lo = blockIdx.x * CH1;
  int hi = min(lo + CH1, n_edges);
  for (int i = lo + t; i < hi; i += 256) atomicAdd(&h[rows[i] >> 11], 1);
  __syncthreads();
  if (t < NSB_MAX) {
    int c = h[t];
    base_s[t] = c ? atomicAdd(&sb_cursor[t], c) : 0;
    h[t] = 0;   // reuse as local cursor
  }
  __syncthreads();
  for (int i = lo + t; i < hi; i += 256) {
    int r = rows[i];
    int s = r >> 11;
    int l = atomicAdd(&h[s], 1);
    tmp1[base_s[s] + l] =
        make_int2(((r & 2047) << 17) | cols[i], __float_as_int(vals[i]));
  }
}

// ---------------------------------------------------------------------------
// K4 (P2): split each super-bucket into its 16 final buckets. 16 blocks per
// sb, each handling a 1/16 slice; scatter confined to the sb's ~260 KB
// window (L2-resident), runs ~128 edges = 16 full lines per (block,bucket).
// bucket-in-sb = bits 24..27 of payload.x; final payload masks to 7 row bits.
// ---------------------------------------------------------------------------
__global__ __launch_bounds__(256) void bucket_partition_kernel(
    const int* __restrict__ sb_off, int* __restrict__ bucket_cursor,
    const int2* __restrict__ tmp1, int2* __restrict__ tmp2) {
  __shared__ int h[16];
  __shared__ int base_s[16];
  const int s = blockIdx.x >> 4;
  const int j = blockIdx.x & 15;
  const int t = threadIdx.x;
  int lo = sb_off[s], hi = sb_off[s + 1];
  int n = hi - lo;
  int sz = (n + 15) >> 4;
  int a = lo + j * sz;
  int b = min(a + sz, hi);
  if (t < 16) h[t] = 0;
  __syncthreads();
  for (int i = a + t; i < b; i += 256)
    atomicAdd(&h[(((unsigned)tmp1[i].x) >> 24) & 15], 1);
  __syncthreads();
  if (t < 16) {
    int c = h[t];
    base_s[t] = c ? atomicAdd(&bucket_cursor[(s << 4) + t], c) : 0;
    h[t] = 0;   // reuse as local cursor
  }
  __syncthreads();
  for (int i = a + t; i < b; i += 256) {
    int2 p = tmp1[i];
    int bi = (((unsigned)p.x) >> 24) & 15;
    int l = atomicAdd(&h[bi], 1);
    tmp2[base_s[bi] + l] = make_int2(p.x & 0x00FFFFFF, p.y);
  }
}

// ---------------------------------------------------------------------------
// K5: x -> bf16 cast (16 floats/thread). Runs AFTER P2: xh overlays tmp1.
// ---------------------------------------------------------------------------
__global__ __launch_bounds__(256) void xcast_kernel(
    const float* __restrict__ x, unsigned short* __restrict__ xh,
    int total_elems) {
  int idx = blockIdx.x * 256 + threadIdx.x;
  if (idx * 16 >= total_elems) return;
  const float4* x4 = (const float4*)x;
  uint4* xh4 = (uint4*)xh;
#pragma unroll
  for (int j = 0; j < 2; ++j) {
    float4 a = x4[idx * 4 + 2 * j];
    float4 c = x4[idx * 4 + 2 * j + 1];
    uint4 o;
    o.x = (unsigned)f2bf(a.x) | ((unsigned)f2bf(a.y) << 16);
    o.y = (unsigned)f2bf(a.z) | ((unsigned)f2bf(a.w) << 16);
    o.z = (unsigned)f2bf(c.x) | ((unsigned)f2bf(c.y) << 16);
    o.w = (unsigned)f2bf(c.z) | ((unsigned)f2bf(c.w) << 16);
    xh4[idx * 2 + j] = o;
  }
}

// ---------------------------------------------------------------------------
// K6: fused in-LDS sort + register gather of y=adj@x + in-block MFMA GEMM.
// out = (adj@x)@W + rowsum⊗b.  One 1024-thr block (16 waves) per 128-row
// bucket. LDS phase overlay (69.6 KB -> 2 blocks/CU):
//   sort:   ebuf[0,20480) (⊂ y region), sbuf[34816,55296)
//   gather: y[0,34816) written while sbuf read (disjoint)
//   gemm:   y + wfs[34816,67584) (over dead sbuf; W prefetched to regs
//           at kernel start, dropped to LDS post-gather)
// ---------------------------------------------------------------------------
__global__ __launch_bounds__(1024, 8) void gather_gemm_kernel(
    const uint2* __restrict__ xh, const unsigned short* __restrict__ wf,
    const float* __restrict__ bias, const int* __restrict__ bucket_off,
    const int2* __restrict__ tmp, float* __restrict__ out, int n_nodes) {
  __shared__ __align__(16) char U[67584];
  __shared__ int cnt[128];
  __shared__ int scn[128];
  __shared__ int rs[129];
  __shared__ float rowsum[128];
  unsigned short* ys = (unsigned short*)U;             // [0,34816)
  int2* ebuf = (int2*)U;                               // [0,20480)
  int2* sbuf = (int2*)(U + 34816);                     // [34816,55296)
  unsigned short* wfs = (unsigned short*)(U + 34816);  // [34816,67584)
  const int t = threadIdx.x;
  const int b = blockIdx.x;

  // prefetch W fragments to registers (T14: issue early, write late)
  const uint4* wf4 = (const uint4*)wf;
  uint4 wfr0 = wf4[t];
  uint4 wfr1 = wf4[t + 1024];

  const int lo = bucket_off[b];
  const int ne = bucket_off[b + 1] - lo;
  const int slot = t >> 5;       // 0..31
  const int lane = t & 31;

  if (ne <= CAP) {
    if (t < 128) cnt[t] = 0;
    __syncthreads();
    for (int i = t; i < ne; i += 1024) {
      int2 p = tmp[lo + i];
      ebuf[i] = p;
      atomicAdd(&cnt[((unsigned)p.x) >> 17], 1);
    }
    __syncthreads();
    if (t < 128) scn[t] = cnt[t];
    __syncthreads();
#pragma unroll
    for (int d = 1; d < 128; d <<= 1) {
      int v = (t < 128 && t >= d) ? scn[t - d] : 0;
      __syncthreads();
      if (t < 128) scn[t] += v;
      __syncthreads();
    }
    if (t < 128) {
      rs[t] = (t == 0) ? 0 : scn[t - 1];
      cnt[t] = 0;                // reuse as per-row cursor
    }
    __syncthreads();
    if (t == 0) rs[128] = scn[127];   // read only after next barrier
    for (int i = t; i < ne; i += 1024) {
      int2 p = ebuf[i];
      int r = ((unsigned)p.x) >> 17;
      int l = atomicAdd(&cnt[r], 1);
      sbuf[rs[r] + l] = p;
    }
    __syncthreads();
    // gather: slot handles rows slot, slot+32, ... ; y + rowsum per row
#pragma unroll
    for (int rr = 0; rr < 4; ++rr) {
      int row = slot + (rr << 5);
      int s = rs[row], e = rs[row + 1];
      float4 acc = make_float4(0.f, 0.f, 0.f, 0.f);
      float rsum = 0.f;
      int i = s;
      for (; i + 4 <= e; i += 4) {
        int2 p0 = sbuf[i + 0];
        int2 p1 = sbuf[i + 1];
        int2 p2 = sbuf[i + 2];
        int2 p3 = sbuf[i + 3];
        uint2 s0 = xh[((size_t)(p0.x & 0x1FFFF) << 5) + lane];
        uint2 s1 = xh[((size_t)(p1.x & 0x1FFFF) << 5) + lane];
        uint2 s2 = xh[((size_t)(p2.x & 0x1FFFF) << 5) + lane];
        uint2 s3 = xh[((size_t)(p3.x & 0x1FFFF) << 5) + lane];
        float v0 = __int_as_float(p0.y), v1 = __int_as_float(p1.y);
        float v2 = __int_as_float(p2.y), v3 = __int_as_float(p3.y);
        rsum += v0 + v1 + v2 + v3;
        acc.x += v0 * __uint_as_float(s0.x << 16);
        acc.y += v0 * __uint_as_float(s0.x & 0xffff0000u);
        acc.z += v0 * __uint_as_float(s0.y << 16);
        acc.w += v0 * __uint_as_float(s0.y & 0xffff0000u);
        acc.x += v1 * __uint_as_float(s1.x << 16);
        acc.y += v1 * __uint_as_float(s1.x & 0xffff0000u);
        acc.z += v1 * __uint_as_float(s1.y << 16);
        acc.w += v1 * __uint_as_float(s1.y & 0xffff0000u);
        acc.x += v2 * __uint_as_float(s2.x << 16);
        acc.y += v2 * __uint_as_float(s2.x & 0xffff0000u);
        acc.z += v2 * __uint_as_float(s2.y << 16);
        acc.w += v2 * __uint_as_float(s2.y & 0xffff0000u);
        acc.x += v3 * __uint_as_float(s3.x << 16);
        acc.y += v3 * __uint_as_float(s3.x & 0xffff0000u);
        acc.z += v3 * __uint_as_float(s3.y << 16);
        acc.w += v3 * __uint_as_float(s3.y & 0xffff0000u);
      }
      for (; i < e; ++i) {
        int2 p = sbuf[i];
        float v = __int_as_float(p.y);
        uint2 sv = xh[((size_t)(p.x & 0x1FFFF) << 5) + lane];
        rsum += v;
        acc.x += v * __uint_as_float(sv.x << 16);
        acc.y += v * __uint_as_float(sv.x & 0xffff0000u);
        acc.z += v * __uint_as_float(sv.y << 16);
        acc.w += v * __uint_as_float(sv.y & 0xffff0000u);
      }
      unsigned u0 = (unsigned)f2bf(acc.x) | ((unsigned)f2bf(acc.y) << 16);
      unsigned u1 = (unsigned)f2bf(acc.z) | ((unsigned)f2bf(acc.w) << 16);
      *((uint2*)(ys + row * SP + lane * 4)) = make_uint2(u0, u1);
      if (lane == 0) rowsum[row] = rsum;
    }
  } else {
    // fallback (ne > CAP, ~ +11 sigma): filtered global scan
#pragma unroll
    for (int rr = 0; rr < 4; ++rr) {
      int row = slot + (rr << 5);
      float4 acc = make_float4(0.f, 0.f, 0.f, 0.f);
      float rsum = 0.f;
      for (int i = 0; i < ne; ++i) {
        int2 p = tmp[lo + i];
        if ((int)(((unsigned)p.x) >> 17) != row) continue;
        float v = __int_as_float(p.y);
        uint2 sv = xh[((size_t)(p.x & 0x1FFFF) << 5) + lane];
        rsum += v;
        acc.x += v * __uint_as_float(sv.x << 16);
        acc.y += v * __uint_as_float(sv.x & 0xffff0000u);
        acc.z += v * __uint_as_float(sv.y << 16);
        acc.w += v * __uint_as_float(sv.y & 0xffff0000u);
      }
      unsigned u0 = (unsigned)f2bf(acc.x) | ((unsigned)f2bf(acc.y) << 16);
      unsigned u1 = (unsigned)f2bf(acc.z) | ((unsigned)f2bf(acc.w) << 16);
      *((uint2*)(ys + row * SP + lane * 4)) = make_uint2(u0, u1);
      if (lane == 0) rowsum[row] = rsum;
    }
  }
  __syncthreads();

  // drop prefetched W fragments into LDS (over dead sbuf)
  uint4* wfs4 = (uint4*)wfs;
  wfs4[t] = wfr0;
  wfs4[t + 1024] = wfr1;
  __syncthreads();

  // in-block GEMM: 16 waves, each 32x32 of the 128x128 tile
  const int l64 = t & 63;
  const int w = t >> 6;
  const int m = l64 & 15, q = l64 >> 4;
  const int rb = (w & 3) * 32;
  const int cb = (w >> 2) * 32;

  floatx4 acc2[2][2];
#pragma unroll
  for (int rt = 0; rt < 2; ++rt)
#pragma unroll
    for (int ct = 0; ct < 2; ++ct) {
      acc2[rt][ct][0] = 0.f; acc2[rt][ct][1] = 0.f;
      acc2[rt][ct][2] = 0.f; acc2[rt][ct][3] = 0.f;
    }

#pragma unroll
  for (int ks = 0; ks < 4; ++ks) {
    short8 af[2], bfr[2];
#pragma unroll
    for (int rt = 0; rt < 2; ++rt)
      af[rt] = *((const short8*)(ys + (rb + rt * 16 + m) * SP + ks * 32 + q * 8));
#pragma unroll
    for (int ct = 0; ct < 2; ++ct) {
      int nt = (cb >> 4) + ct;
      bfr[ct] = *((const short8*)(wfs + ((ks * 8 + nt) * 64 + l64) * 8));
    }
#pragma unroll
    for (int rt = 0; rt < 2; ++rt)
#pragma unroll
      for (int ct = 0; ct < 2; ++ct)
        acc2[rt][ct] = __builtin_amdgcn_mfma_f32_16x16x32_bf16(
            af[rt], bfr[ct], acc2[rt][ct], 0, 0, 0);
  }

  // epilogue: out = acc + rowsum[row]*b[col]; C/D map row=(lane>>4)*4+r, col=m
  float b0 = bias[cb + m];
  float b1 = bias[cb + 16 + m];
#pragma unroll
  for (int rt = 0; rt < 2; ++rt)
#pragma unroll
    for (int ct = 0; ct < 2; ++ct) {
      float bc = ct ? b1 : b0;
#pragma unroll
      for (int r = 0; r < 4; ++r) {
        int row = rb + rt * 16 + q * 4 + r;
        int col = cb + ct * 16 + m;
        int node = (b << 7) + row;
        if (node < n_nodes)
          out[(size_t)node * D + col] = acc2[rt][ct][r] + rowsum[row] * bc;
      }
    }
}

extern "C" void kernel_launch(void* const* d_in, const int* in_sizes, int n_in,
                              void* d_out, int out_size, void* d_ws, size_t ws_size,
                              hipStream_t stream) {
  const float* x    = (const float*)d_in[0];
  const int*   rows = (const int*)d_in[1];
  const int*   cols = (const int*)d_in[2];
  const float* vals = (const float*)d_in[3];
  const float* W    = (const float*)d_in[4];
  const float* b    = (const float*)d_in[5];
  float* out = (float*)d_out;

  int n_nodes = in_sizes[0] / D;
  int n_edges = in_sizes[1];
  int nb = (n_nodes + 127) >> 7;              // 782 final buckets
  int nsb = (nb + 15) >> 4;                   // 49 super-buckets
  int total_elems = n_nodes * D;

  // Workspace overlay (peak 38.45 MB, within the proven 38.84 MB budget):
  //   [0, 12.8M)      tmp1 (SB-partitioned edges)  -- dead after P2
  //   [0, 25.6M)      xh (bf16 x)                  -- written by xcast after P2
  //   [25.6M, 38.4M)  tmp2 (bucket-partitioned edges)
  //   [38.4M, ...)    meta + wf
  char* ws = (char*)d_ws;
  int2* tmp1         = (int2*)(ws);
  unsigned short* xh = (unsigned short*)(ws);
  int2* tmp2         = (int2*)(ws + 25600000);
  char* mb           = ws + 38400000;
  int* bucket_cnt    = (int*)(mb);              //  4,096 B
  int* bucket_off    = (int*)(mb + 4096);       //  4,096 B (nb+1 ints)
  int* bucket_cursor = (int*)(mb + 8192);       //  4,096 B
  int* sb_off        = (int*)(mb + 12288);      //    512 B (nsb+1 ints)
  int* sb_cursor     = (int*)(mb + 12800);      //    512 B
  unsigned short* wf = (unsigned short*)(mb + 13312);   // 32,768 B

  hipMemsetAsync(bucket_cnt, 0, NB_MAX * sizeof(int), stream);

  int ablocks = (n_edges + 4095) / 4096;      // 391
  prep_kernel<<<dim3(8 + ablocks), dim3(256), 0, stream>>>(
      W, wf, rows, bucket_cnt, n_edges);

  bucket_scan_kernel<<<dim3(1), dim3(1024), 0, stream>>>(
      bucket_cnt, bucket_off, bucket_cursor, sb_off, sb_cursor, nb);

  int p1blocks = (n_edges + CH1 - 1) / CH1;   // 391
  sb_partition_kernel<<<dim3(p1blocks), dim3(256), 0, stream>>>(
      rows, cols, vals, sb_cursor, tmp1, n_edges);

  bucket_partition_kernel<<<dim3(nsb * 16), dim3(256), 0, stream>>>(
      sb_off, bucket_cursor, tmp1, tmp2);

  int cblocks = (total_elems + 4095) / 4096;  // 3125
  xcast_kernel<<<dim3(cblocks), dim3(256), 0, stream>>>(x, xh, total_elems);

  gather_gemm_kernel<<<dim3(nb), dim3(1024), 0, stream>>>(
      (const uint2*)xh, wf, b, bucket_off, tmp2, out, n_nodes);
}